// Round 4
// baseline (792.873 us; speedup 1.0000x reference)
//
#include <hip/hip_runtime.h>

// HeatmapBatch: out = relu(depthwise 9x9 gaussian conv over (0.01*noise with
// a single spike = 1/max(kernel2d) at coords per (b,k) image)).
// B=64, K=21, H=W=256. Separable conv (gaussian = g g^T): 9+9 taps.

#define Bn 64
#define Kn 21
#define Hn 256
#define Wn 256
#define KS 9
#define PADc 4
#define TILE 64
#define IN_T (TILE + 2 * PADc) // 72
#define NOISE_STD 0.01f

__global__ __launch_bounds__(256)
void heatmap_kernel(const int* __restrict__ coords,
                    const float* __restrict__ noise,
                    const float* __restrict__ kernel2d,
                    float* __restrict__ out) {
    __shared__ float s_in[IN_T][IN_T + 1]; // 72 x 73 (pad +1: no bank conflicts)
    __shared__ float s_h[IN_T][TILE + 1];  // 72 x 65  (horizontal-pass output)

    const int bk = blockIdx.y;   // image index in [0, B*K)
    const int tile = blockIdx.x; // 0..15
    const int tileX = tile & 3;
    const int tileY = tile >> 2;
    const int x_base = tileX * TILE - PADc;
    const int y_base = tileY * TILE - PADc;

    const int tid = threadIdx.x;

    // spike coordinate for this image: coords[bk] = (x, y)
    const int x0 = coords[bk * 2 + 0];
    const int y0 = coords[bk * 2 + 1];

    // Recover 1D gaussian taps from the 2D kernel (k2d = g g^T):
    // g[4] = sqrt(k2d[4][4]); g[i] = k2d[i][4] / g[4].
    const float kc = kernel2d[4 * KS + 4];
    const float g4 = sqrtf(kc);
    float g[KS];
#pragma unroll
    for (int t = 0; t < KS; ++t) g[t] = kernel2d[t * KS + 4] / g4;
    const float gauss_val = 1.0f / kc; // spike value = 1/max(kernel2d)

    const float* img = noise + (size_t)bk * (Hn * Wn);

    // ---- Stage 72x72 input tile (halo 4, zero-padded) into LDS ----
    for (int idx = tid; idx < IN_T * IN_T; idx += 256) {
        const int r = idx / IN_T;
        const int c = idx - r * IN_T;
        const int y = y_base + r;
        const int x = x_base + c;
        float v = 0.0f;
        if ((unsigned)y < (unsigned)Hn && (unsigned)x < (unsigned)Wn) {
            v = NOISE_STD * img[y * Wn + x];
            if (x == x0 && y == y0) v = gauss_val;
        }
        s_in[r][c] = v;
    }
    __syncthreads();

    // ---- Horizontal 9-tap pass: s_h[r][c] = sum_t g[t]*s_in[r][c+t] ----
    for (int idx = tid; idx < IN_T * TILE; idx += 256) {
        const int r = idx >> 6;  // /64
        const int c = idx & 63;
        float acc = 0.0f;
#pragma unroll
        for (int t = 0; t < KS; ++t) acc += g[t] * s_in[r][c + t];
        s_h[r][c] = acc;
    }
    __syncthreads();

    // ---- Vertical 9-tap pass + ReLU + store ----
    float* oimg = out + (size_t)bk * (Hn * Wn);
    for (int idx = tid; idx < TILE * TILE; idx += 256) {
        const int r = idx >> 6;
        const int c = idx & 63;
        float acc = 0.0f;
#pragma unroll
        for (int t = 0; t < KS; ++t) acc += g[t] * s_h[r + t][c];
        acc = fmaxf(acc, 0.0f);
        const int y = tileY * TILE + r;
        const int x = tileX * TILE + c;
        oimg[(size_t)y * Wn + x] = acc;
    }
}

extern "C" void kernel_launch(void* const* d_in, const int* in_sizes, int n_in,
                              void* d_out, int out_size, void* d_ws, size_t ws_size,
                              hipStream_t stream) {
    const int* coords = (const int*)d_in[0];       // (B, K, 2) int32, (x, y)
    const float* noise = (const float*)d_in[1];    // (B, K, H, W) f32
    const float* kernel2d = (const float*)d_in[2]; // (9, 9) f32
    float* out = (float*)d_out;                    // (B, K, H, W) f32

    dim3 grid(16, Bn * Kn); // 4x4 tiles of 64x64 per image, 1344 images
    heatmap_kernel<<<grid, 256, 0, stream>>>(coords, noise, kernel2d, out);
}